// Round 1
// baseline (233.241 us; speedup 1.0000x reference)
//
#include <hip/hip_runtime.h>

// Problem constants: B=64, C=64, H=32, P=496, HK=560, K padded to 576.
#define NB 64
#define NC 64
#define NH 32
#define HK 560
#define KPAD 576

typedef __bf16 bf16x8 __attribute__((ext_vector_type(8)));
typedef float f32x4 __attribute__((ext_vector_type(4)));

__device__ __forceinline__ unsigned short f2bf(float f) {
    unsigned u = __builtin_bit_cast(unsigned, f);
    u = (u + 0x7fffu + ((u >> 16) & 1u)) >> 16;   // round-to-nearest-even
    return (unsigned short)u;
}

// One block per (c,i) group: GEMM [64 x 576] x [576 x 32] with feat built on the fly.
__global__ __launch_bounds__(256, 4) void hconv_kernel(
    const float* __restrict__ x, const float* __restrict__ w,
    const int* __restrict__ idx_a, const int* __restrict__ idx_b,
    float* __restrict__ out)
{
    // x rows with 2 sentinel cols: [32]=1.0 (identity terms), [33]=0.0 (K-pad)
    __shared__ float s_x[NB][34];                          // 8704 B
    __shared__ unsigned s_lut[KPAD];                       // 2304 B
    __shared__ __align__(16) unsigned short s_feat[NB][72];// 9216 B (bf16 bits, pad 64->72)
    __shared__ __align__(16) unsigned short s_wT[32][72];  // 4608 B (bf16 bits, transposed)

    const int t = threadIdx.x;
    const int g = blockIdx.x;           // 0..2047
    const int c = g >> 5, i = g & 31;

    // ---- stage x rows: 64 rows x 32 floats, float4-coalesced (2 rows/thread-pass)
    {
        const int row = t >> 3;                 // 0..31
        const int c4 = (t & 7) * 4;
        const float* xr = x + (((size_t)row * NC + c) * NH + i) * NH;
        const float* xr2 = xr + (size_t)32 * NC * NH * NH;   // row + 32
        float4 v = *(const float4*)(xr + c4);
        float4 v2 = *(const float4*)(xr2 + c4);
        s_x[row][c4] = v.x;  s_x[row][c4 + 1] = v.y;
        s_x[row][c4 + 2] = v.z; s_x[row][c4 + 3] = v.w;
        s_x[row + 32][c4] = v2.x;  s_x[row + 32][c4 + 1] = v2.y;
        s_x[row + 32][c4 + 2] = v2.z; s_x[row + 32][c4 + 3] = v2.w;
        if ((t & 7) == 0) {
            s_x[row][32] = 1.0f;      s_x[row][33] = 0.0f;
            s_x[row + 32][32] = 1.0f; s_x[row + 32][33] = 0.0f;
        }
    }

    // ---- build pair LUT: feat[k] = x[pa]*x[pb] uniformly
    for (int k = t; k < KPAD; k += 256) {
        unsigned pa, pb;
        if (k < 32)        { pa = (unsigned)k;        pb = 32u; }        // x * 1
        else if (k < 64)   { pa = (unsigned)(k - 32); pb = pa;  }        // x * x
        else if (k < HK)   { pa = (unsigned)idx_a[k - 64]; pb = (unsigned)idx_b[k - 64]; }
        else               { pa = 33u; pb = 33u; }                        // 0 * 0 pad
        s_lut[k] = pa | (pb << 16);
    }

    const int wv = t >> 6;              // wave id 0..3 -> m-tile
    const int lane = t & 63;
    const int lr = lane & 15;           // row/col within 16x16
    const int lq = lane >> 4;           // quad 0..3
    const int fb = t >> 2;              // feat compute: b row 0..63
    const int fq = t & 3;               // feat compute: 16-k quarter
    const int wo = t & 31;              // weight staging: o
    const int wkg = t >> 5;             // weight staging: k-group 0..7

    const float* wbase = w + (size_t)(c * NH + i) * HK * NH;

    f32x4 acc0 = {0.f, 0.f, 0.f, 0.f};
    f32x4 acc1 = {0.f, 0.f, 0.f, 0.f};

    for (int ch = 0; ch < 9; ++ch) {
        const int k0 = ch * 64;
        __syncthreads();   // previous chunk's MFMA reads done; s_x/s_lut ready on ch=0

        // ---- stage weight chunk, register-transpose -> s_wT[o][k] bf16
        {
            float v[8];
            const int kb = k0 + wkg * 8;
            #pragma unroll
            for (int r = 0; r < 8; ++r) {
                const int k = kb + r;
                v[r] = (k < HK) ? wbase[(size_t)k * NH + wo] : 0.0f;
            }
            uint4 pk;
            pk.x = (unsigned)f2bf(v[0]) | ((unsigned)f2bf(v[1]) << 16);
            pk.y = (unsigned)f2bf(v[2]) | ((unsigned)f2bf(v[3]) << 16);
            pk.z = (unsigned)f2bf(v[4]) | ((unsigned)f2bf(v[5]) << 16);
            pk.w = (unsigned)f2bf(v[6]) | ((unsigned)f2bf(v[7]) << 16);
            *(uint4*)&s_wT[wo][wkg * 8] = pk;
        }

        // ---- compute feat chunk: 16 k's per thread for one b row
        {
            unsigned pk[8];
            #pragma unroll
            for (int m = 0; m < 8; ++m) {
                const int kk = k0 + fq * 16 + 2 * m;
                const unsigned l0 = s_lut[kk], l1 = s_lut[kk + 1];
                const float p0 = s_x[fb][l0 & 0xffffu] * s_x[fb][l0 >> 16];
                const float p1 = s_x[fb][l1 & 0xffffu] * s_x[fb][l1 >> 16];
                pk[m] = (unsigned)f2bf(p0) | ((unsigned)f2bf(p1) << 16);
            }
            uint4 lo, hi;
            lo.x = pk[0]; lo.y = pk[1]; lo.z = pk[2]; lo.w = pk[3];
            hi.x = pk[4]; hi.y = pk[5]; hi.z = pk[6]; hi.w = pk[7];
            *(uint4*)&s_feat[fb][fq * 16] = lo;
            *(uint4*)&s_feat[fb][fq * 16 + 8] = hi;
        }

        __syncthreads();

        // ---- MFMA: wave wv does m-tile wv, both n-tiles, 2 k-steps of 32
        #pragma unroll
        for (int ks = 0; ks < 2; ++ks) {
            bf16x8 a  = *(const bf16x8*)&s_feat[wv * 16 + lr][ks * 32 + lq * 8];
            bf16x8 b0 = *(const bf16x8*)&s_wT[lr][ks * 32 + lq * 8];
            bf16x8 b1 = *(const bf16x8*)&s_wT[16 + lr][ks * 32 + lq * 8];
            acc0 = __builtin_amdgcn_mfma_f32_16x16x32_bf16(a, b0, acc0, 0, 0, 0);
            acc1 = __builtin_amdgcn_mfma_f32_16x16x32_bf16(a, b1, acc1, 0, 0, 0);
        }
    }

    // ---- epilogue: C/D layout col=lane&15, row=quad*4+reg (m89-verified)
    #pragma unroll
    for (int r = 0; r < 4; ++r) {
        const int b = wv * 16 + lq * 4 + r;
        float* op = out + (((size_t)b * NC + c) * NH + i) * NH;
        op[lr] = acc0[r];
        op[16 + lr] = acc1[r];
    }
}

extern "C" void kernel_launch(void* const* d_in, const int* in_sizes, int n_in,
                              void* d_out, int out_size, void* d_ws, size_t ws_size,
                              hipStream_t stream) {
    const float* x = (const float*)d_in[0];
    const float* w = (const float*)d_in[1];
    const int* idx_a = (const int*)d_in[2];
    const int* idx_b = (const int*)d_in[3];
    float* out = (float*)d_out;
    hconv_kernel<<<dim3(NC * NH), dim3(256), 0, stream>>>(x, w, idx_a, idx_b, out);
}